// Round 13
// baseline (336.908 us; speedup 1.0000x reference)
//
#include <hip/hip_runtime.h>

#define N_EDGES 1000000
#define HID 128
#define ME 64          // edges per block (col-split: each wave owns one 32-col n-tile)
#define NK1 35         // layer-1 K-steps of 16: 32 (zs,zd,pr,ad) + 3 tail (48 cols)

typedef unsigned short ushort;
typedef unsigned int uint;
typedef __attribute__((ext_vector_type(8))) short short8;
typedef __attribute__((ext_vector_type(16))) float f32x16;

__device__ __forceinline__ float blo(uint u) { return __builtin_bit_cast(float, u << 16); }
__device__ __forceinline__ float bhi(uint u) { return __builtin_bit_cast(float, u & 0xffff0000u); }
__device__ __forceinline__ ushort f2bfbits(float f) {
  uint u = __builtin_bit_cast(uint, f);
  return (ushort)((u + 0x7fffu + ((u >> 16) & 1u)) >> 16);  // RNE
}
__device__ __forceinline__ uint cvtpk(float a, float b) {
  uint r;
  asm("v_cvt_pk_bf16_f32 %0, %1, %2" : "=v"(r) : "v"(a), "v"(b));
  return r;  // lo = bf16(a), hi = bf16(b)
}
__device__ __forceinline__ uint cvtpk_abs(float a, float b) {
  uint r;
  asm("v_cvt_pk_bf16_f32 %0, abs(%1), abs(%2)" : "=v"(r) : "v"(a), "v"(b));
  return r;
}
__device__ __forceinline__ ushort bf1(float a) { return (ushort)cvtpk(a, a); }
// XOR-swizzled element index into a [64][128] ushort LDS tile.
__device__ __forceinline__ int sidx(int r, int c) {
  return r * 128 + (c ^ ((r & 7) << 3));
}

// Pack W (row-major [K][128] f32) into B-fragment order for mfma_f32_32x32x16_bf16:
// B-frag: col = nt*32 + (lane&31), k = ks*16 + (lane>>5)*8 + j.
// W1p ks 0..31: k as-is (zs,zd,prod,absdiff = K 0..511).
// W1p ks 32..34 (tail, 48 cols): c = (ks-32)*16+(lane>>5)*8+j;
//   c==0 -> k512 (dist); c in [2,34) -> k 511+c (lr_emb); else zero row.
__global__ void prep_kernel(const float* __restrict__ W1, const float* __restrict__ W2,
                            ushort* __restrict__ W1p, ushort* __restrict__ W2p) {
  const int t = blockIdx.x * blockDim.x + threadIdx.x;
  const int n1 = NK1 << 11;  // 35*4*64*8 = 71680
  if (t < n1) {
    const int j = t & 7, lane = (t >> 3) & 63, nt = (t >> 9) & 3, ks = t >> 11;
    const int col = nt * 32 + (lane & 31);
    const int kk = (lane >> 5) * 8 + j;
    float val = 0.f;
    if (ks < 32) {
      val = W1[(ks * 16 + kk) * HID + col];
    } else {
      const int c = (ks - 32) * 16 + kk;
      const int k = (c == 0) ? 512 : ((c >= 2 && c < 34) ? (511 + c) : -1);
      if (k >= 0) val = W1[k * HID + col];
    }
    W1p[t] = f2bfbits(val);
  } else {
    const int t2 = t - n1;
    if (t2 < (8 << 11)) {
      const int j = t2 & 7, lane = (t2 >> 3) & 63, nt = (t2 >> 9) & 3, ks = t2 >> 11;
      W2p[t2] = f2bfbits(W2[(ks * 16 + (lane >> 5) * 8 + j) * HID + nt * 32 + (lane & 31)]);
    }
  }
}

// R13 = R10 (proven best: col-split, 32x32x16, 7 phases, 2 LDS buffers) at
// 5 blocks/CU. Reg ledger (R12 finding: VGPR_Count excludes AGPR):
// demand = 60 VGPR + 32 AGPR = 92 <= cap 512/5 = 102 -> spill-free;
// LDS 5 x 32768 = exactly 160 KiB. +25% co-resident blocks vs R10 attacks
// the measured ~50% latency-idle. WRITE_SIZE / VGPR_Count = tripwires.
__global__ __launch_bounds__(256, 5)
void edge_mlp(const float* __restrict__ z, const int* __restrict__ ei,
              const float* __restrict__ ea, const float* __restrict__ lre,
              const ushort* __restrict__ W1p, const float* __restrict__ b1,
              const ushort* __restrict__ W2p, const float* __restrict__ b2,
              const float* __restrict__ W3, const float* __restrict__ b3,
              float* __restrict__ out) {
  __shared__ ushort B0[ME * 128];  // 2 buffers * 16384B = 32768B
  __shared__ ushort B1[ME * 128];

  const int tid = threadIdx.x;
  const int lane = tid & 63;
  const int w = tid >> 6;        // wave 0..3, owns output cols [32w, 32w+32)
  const int r15 = lane & 15;
  const int g = lane >> 4;
  const int half = lane >> 5;    // 0/1
  const int li = lane & 31;
  const int hi = lane >> 5;
  const int row0 = w * 16;       // edges this wave gathers/builds
  const int cw = w * 32;
  const int eb = blockIdx.x * ME;

  // ---- per-wave metadata: lanes 0..15 = src idx, 16..31 = dst idx,
  //      lanes 32..47 = dist(f32), 48..63 = lr_id(f32)
  int sd = 0;
  float auxv = 0.f;
  if (lane < 16)      sd = ei[eb + row0 + lane];
  else if (lane < 32) sd = ei[N_EDGES + eb + row0 + (lane - 16)];
  else if (lane < 48) auxv = ea[(eb + row0 + (lane - 32)) * 7 + 0];
  else                auxv = ea[(eb + row0 + (lane - 48)) * 7 + 2];

  // ---- P0: gather zs,zd (same edge in same lane), write zs->B0, zd->B1;
  //      prod/absdiff computed in f32 NOW, held packed in 32 VGPRs.
  uint2 pr_pk[8], ad_pk[8];
#pragma unroll
  for (int t = 0; t < 8; ++t) {
    const int e = 2 * t + half;
    const int r = row0 + e;
    const int s = __shfl(sd, e);
    const int d = __shfl(sd, 16 + e);
    const float4 a = *(const float4*)(z + s * HID + 4 * li);
    const float4 b = *(const float4*)(z + d * HID + 4 * li);
    uint2 zs, zd;
    zs.x = cvtpk(a.x, a.y); zs.y = cvtpk(a.z, a.w);
    zd.x = cvtpk(b.x, b.y); zd.y = cvtpk(b.z, b.w);
    *(uint2*)&B0[sidx(r, 4 * li)] = zs;
    *(uint2*)&B1[sidx(r, 4 * li)] = zd;
    pr_pk[t].x = cvtpk(a.x * b.x, a.y * b.y);
    pr_pk[t].y = cvtpk(a.z * b.z, a.w * b.w);
    ad_pk[t].x = cvtpk_abs(a.x - b.x, a.y - b.y);
    ad_pk[t].y = cvtpk_abs(a.z - b.z, a.w - b.w);
  }
  __syncthreads();

  f32x16 acc[2];   // 2 m-tiles x 1 n-tile, reused for layer 1 AND 2 -> 32 AGPRs
#pragma unroll
  for (int mt = 0; mt < 2; ++mt)
#pragma unroll
    for (int rg = 0; rg < 16; ++rg) acc[mt][rg] = 0.f;

  // One K=16 step: A-frag row = mt*32+(lane&31), k-col = (ks&7)*16 + hi*8;
  // B-frag (W) from WP at n-tile w.
#define MFMA_KS(BUF, WP, NKS, KS0)                                                      \
  _Pragma("unroll")                                                                     \
  for (int ks = 0; ks < (NKS); ++ks) {                                                  \
    const int ksg = (KS0) + ks;                                                         \
    short8 bfr = *(const short8*)((WP) + (((ksg * 4 + w) * 64) + lane) * 8);            \
    _Pragma("unroll")                                                                   \
    for (int mt = 0; mt < 2; ++mt) {                                                    \
      short8 af = *(const short8*)&BUF[sidx(mt * 32 + li, ((ksg & 7) * 16) + hi * 8)];  \
      acc[mt] = __builtin_amdgcn_mfma_f32_32x32x16_bf16(af, bfr, acc[mt], 0, 0, 0);     \
    }                                                                                   \
  }

  // ---- P1: MFMA zs (ks 0..7)
  __builtin_amdgcn_s_setprio(1);
  MFMA_KS(B0, W1p, 8, 0)
  __builtin_amdgcn_s_setprio(0);
  __syncthreads();

  // ---- P2: prod -> B0 (pure stores from regs); MFMA zd (ks 8..15)
#pragma unroll
  for (int t = 0; t < 8; ++t)
    *(uint2*)&B0[sidx(row0 + 2 * t + half, 4 * li)] = pr_pk[t];
  __builtin_amdgcn_s_setprio(1);
  MFMA_KS(B1, W1p, 8, 8)
  __builtin_amdgcn_s_setprio(0);
  __syncthreads();

  // ---- P3: absdiff -> B1 (pure stores); MFMA prod (ks 16..23)
#pragma unroll
  for (int t = 0; t < 8; ++t)
    *(uint2*)&B1[sidx(row0 + 2 * t + half, 4 * li)] = ad_pk[t];
  __builtin_amdgcn_s_setprio(1);
  MFMA_KS(B0, W1p, 8, 16)
  __builtin_amdgcn_s_setprio(0);
  __syncthreads();

  // ---- P4: tail -> B0 (col0 dist, cols 2..33 lr_emb; cols 34..47 stale prod
  //      * zero weight rows = 0; cols 48+ never read); MFMA absdiff (ks 24..31)
  {
    const float dv = __shfl(auxv, 32 + r15);
    if (lane < 16) B0[sidx(row0 + lane, 0)] = bf1(dv);
  }
#pragma unroll
  for (int t = 0; t < 4; ++t) {
    const int e = 4 * t + g;
    const int lrid = (int)__shfl(auxv, 48 + e);
    const float2 lv = *(const float2*)(lre + lrid * 32 + 2 * r15);
    *(uint*)&B0[sidx(row0 + e, 2 + 2 * r15)] = cvtpk(lv.x, lv.y);
  }
  __builtin_amdgcn_s_setprio(1);
  MFMA_KS(B1, W1p, 8, 24)
  __builtin_amdgcn_s_setprio(0);
  __syncthreads();

  // ---- P5: MFMA tail (ks 32..34); h1 = relu(acc+b1) -> B1
  __builtin_amdgcn_s_setprio(1);
  MFMA_KS(B0, W1p, 3, 32)
  __builtin_amdgcn_s_setprio(0);
  {
    const float b1v = b1[cw + li];
#pragma unroll
    for (int mt = 0; mt < 2; ++mt)
#pragma unroll
      for (int rg = 0; rg < 16; ++rg) {
        const int row = mt * 32 + (rg & 3) + 8 * (rg >> 2) + 4 * hi;
        const float h = fmaxf(acc[mt][rg] + b1v, 0.f);
        B1[sidx(row, cw + li)] = bf1(h);
      }
  }
  __syncthreads();

  // ---- P6: layer 2 (K=128, ks 0..7) from B1 (acc reused); h2 -> B0
#pragma unroll
  for (int mt = 0; mt < 2; ++mt)
#pragma unroll
    for (int rg = 0; rg < 16; ++rg) acc[mt][rg] = 0.f;
  __builtin_amdgcn_s_setprio(1);
  MFMA_KS(B1, W2p, 8, 0)
  __builtin_amdgcn_s_setprio(0);
  {
    const float b2v = b2[cw + li];
#pragma unroll
    for (int mt = 0; mt < 2; ++mt)
#pragma unroll
      for (int rg = 0; rg < 16; ++rg) {
        const int row = mt * 32 + (rg & 3) + 8 * (rg >> 2) + 4 * hi;
        const float h = fmaxf(acc[mt][rg] + b2v, 0.f);
        B0[sidx(row, cw + li)] = bf1(h);
      }
  }
  __syncthreads();

  // ---- P7: layer 3 from B0: lane -> row w*16+r15, cols g*32..g*32+31
  {
    const int rr = w * 16 + r15;
    float sum = 0.f;
#pragma unroll
    for (int i = 0; i < 4; ++i) {
      const int c0 = g * 32 + i * 8;
      const uint4 hv = *(const uint4*)&B0[sidx(rr, c0)];
#pragma unroll
      for (int p = 0; p < 4; ++p) {
        const uint u = ((const uint*)&hv)[p];
        const float2 wv = *(const float2*)(W3 + c0 + 2 * p);
        sum += blo(u) * wv.x + bhi(u) * wv.y;
      }
    }
    sum += __shfl_xor(sum, 16);
    sum += __shfl_xor(sum, 32);
    if (lane < 16) out[eb + rr] = sum + b3[0];
  }
}

extern "C" void kernel_launch(void* const* d_in, const int* in_sizes, int n_in,
                              void* d_out, int out_size, void* d_ws, size_t ws_size,
                              hipStream_t stream) {
  const float* z   = (const float*)d_in[0];
  const int*   ei  = (const int*)d_in[1];
  const float* ea  = (const float*)d_in[2];
  const float* lre = (const float*)d_in[3];
  const float* W1  = (const float*)d_in[4];
  const float* b1  = (const float*)d_in[5];
  const float* W2  = (const float*)d_in[6];
  const float* b2  = (const float*)d_in[7];
  const float* W3  = (const float*)d_in[8];
  const float* b3  = (const float*)d_in[9];
  float* out = (float*)d_out;

  ushort* W1p = (ushort*)d_ws;              // 35*4*64*8 = 71680 bf16
  ushort* W2p = W1p + (NK1 << 11);          // 8*4*64*8  = 16384 bf16

  prep_kernel<<<344, 256, 0, stream>>>(W1, W2, W1p, W2p);
  edge_mlp<<<N_EDGES / ME, 256, 0, stream>>>(z, ei, ea, lre, W1p, b1, W2p, b2, W3, b3, out);
}

// Round 14
// 249.686 us; speedup vs baseline: 1.3493x; 1.3493x over previous
//
#include <hip/hip_runtime.h>

#define N_EDGES 1000000
#define N_NODES 100000
#define HID 128
#define ME 64          // edges per block (col-split: each wave owns one 32-col n-tile)
#define NK1 35         // layer-1 K-steps of 16: 32 (zs,zd,pr,ad) + 3 tail (48 cols)

typedef unsigned short ushort;
typedef unsigned int uint;
typedef __attribute__((ext_vector_type(8))) short short8;
typedef __attribute__((ext_vector_type(16))) float f32x16;

__device__ __forceinline__ float blo(uint u) { return __builtin_bit_cast(float, u << 16); }
__device__ __forceinline__ float bhi(uint u) { return __builtin_bit_cast(float, u & 0xffff0000u); }
__device__ __forceinline__ ushort f2bfbits(float f) {
  uint u = __builtin_bit_cast(uint, f);
  return (ushort)((u + 0x7fffu + ((u >> 16) & 1u)) >> 16);  // RNE
}
__device__ __forceinline__ uint cvtpk(float a, float b) {
  uint r;
  asm("v_cvt_pk_bf16_f32 %0, %1, %2" : "=v"(r) : "v"(a), "v"(b));
  return r;  // lo = bf16(a), hi = bf16(b)
}
__device__ __forceinline__ uint cvtpk_abs(float a, float b) {
  uint r;
  asm("v_cvt_pk_bf16_f32 %0, abs(%1), abs(%2)" : "=v"(r) : "v"(a), "v"(b));
  return r;
}
__device__ __forceinline__ ushort bf1(float a) { return (ushort)cvtpk(a, a); }
// XOR-swizzled element index into a [64][128] ushort LDS tile. Bijective for
// aligned groups of <=8 elems within an 8-elem cell.
__device__ __forceinline__ int sidx(int r, int c) {
  return r * 128 + (c ^ ((r & 7) << 3));
}

// Pack W (row-major [K][128] f32) into B-fragment order for mfma_f32_32x32x16_bf16:
// B-frag: col = nt*32 + (lane&31), k = ks*16 + (lane>>5)*8 + j.
// W1p ks 0..31: k as-is (zs,zd,prod,absdiff = K 0..511).
// W1p ks 32..34 (tail, 48 cols): c = (ks-32)*16+(lane>>5)*8+j;
//   c==0 -> k512 (dist); c in [2,34) -> k 511+c (lr_emb); else zero row.
__global__ void prep_kernel(const float* __restrict__ W1, const float* __restrict__ W2,
                            ushort* __restrict__ W1p, ushort* __restrict__ W2p) {
  const int t = blockIdx.x * blockDim.x + threadIdx.x;
  const int n1 = NK1 << 11;  // 35*4*64*8 = 71680
  if (t < n1) {
    const int j = t & 7, lane = (t >> 3) & 63, nt = (t >> 9) & 3, ks = t >> 11;
    const int col = nt * 32 + (lane & 31);
    const int kk = (lane >> 5) * 8 + j;
    float val = 0.f;
    if (ks < 32) {
      val = W1[(ks * 16 + kk) * HID + col];
    } else {
      const int c = (ks - 32) * 16 + kk;
      const int k = (c == 0) ? 512 : ((c >= 2 && c < 34) ? (511 + c) : -1);
      if (k >= 0) val = W1[k * HID + col];
    }
    W1p[t] = f2bfbits(val);
  } else {
    const int t2 = t - n1;
    if (t2 < (8 << 11)) {
      const int j = t2 & 7, lane = (t2 >> 3) & 63, nt = (t2 >> 9) & 3, ks = t2 >> 11;
      W2p[t2] = f2bfbits(W2[(ks * 16 + (lane >> 5) * 8 + j) * HID + nt * 32 + (lane & 31)]);
    }
  }
}

// z f32 -> bf16 (RNE, identical bits to the inline conversion the gather did).
// 25.6 MB result is L3-resident -> gather demand halves, HBM z-refetch ~gone.
__global__ void prep_z(const float* __restrict__ z, ushort* __restrict__ zb) {
  const int i = blockIdx.x * blockDim.x + threadIdx.x;  // one per 4 elems
  if (i < N_NODES * (HID / 4)) {
    const float4 v = ((const float4*)z)[i];
    uint2 o;
    o.x = cvtpk(v.x, v.y);
    o.y = cvtpk(v.z, v.w);
    ((uint2*)zb)[i] = o;
  }
}

// R14 = R10 (proven best) + (1) bf16 z gathers (ZBF=1; half gather bytes,
// quarter-wave uint4 rows, b128 LDS writes) + (2) W-fragment prefetch across
// each barrier (compiler can't hoist loads past __syncthreads; +4 VGPR).
// Reg ledger: ~60 VGPR + 32 AGPR + pf 4 <= 128 cap at (256,4). R13 lesson:
// cap 102 spills, so 4 blocks/CU is the ceiling config.
template <int ZBF>
__global__ __launch_bounds__(256, 4)
void edge_mlp(const float* __restrict__ z, const ushort* __restrict__ zb,
              const int* __restrict__ ei,
              const float* __restrict__ ea, const float* __restrict__ lre,
              const ushort* __restrict__ W1p, const float* __restrict__ b1,
              const ushort* __restrict__ W2p, const float* __restrict__ b2,
              const float* __restrict__ W3, const float* __restrict__ b3,
              float* __restrict__ out) {
  __shared__ ushort B0[ME * 128];  // 2 buffers * 16384B = 32768B
  __shared__ ushort B1[ME * 128];

  const int tid = threadIdx.x;
  const int lane = tid & 63;
  const int w = tid >> 6;        // wave 0..3, owns output cols [32w, 32w+32)
  const int r15 = lane & 15;
  const int g = lane >> 4;
  const int half = lane >> 5;    // 0/1
  const int li = lane & 31;
  const int hi = lane >> 5;
  const int row0 = w * 16;       // edges this wave gathers/builds
  const int cw = w * 32;
  const int eb = blockIdx.x * ME;

  // ---- per-wave metadata: lanes 0..15 = src idx, 16..31 = dst idx,
  //      lanes 32..47 = dist(f32), 48..63 = lr_id(f32)
  int sd = 0;
  float auxv = 0.f;
  if (lane < 16)      sd = ei[eb + row0 + lane];
  else if (lane < 32) sd = ei[N_EDGES + eb + row0 + (lane - 16)];
  else if (lane < 48) auxv = ea[(eb + row0 + (lane - 32)) * 7 + 0];
  else                auxv = ea[(eb + row0 + (lane - 48)) * 7 + 2];

  // ---- P0: gather zs,zd (same edge in same lane), write zs->B0, zd->B1;
  //      prod/absdiff computed NOW, held packed in 32 VGPRs.
  uint4 pr_pk[4], ad_pk[4];
  if constexpr (ZBF) {
    const int q = lane >> 4;     // quarter-wave: 4 edges per iteration
    const int l16 = lane & 15;
#pragma unroll
    for (int t = 0; t < 4; ++t) {
      const int e = 4 * t + q;
      const int r = row0 + e;
      const int s = __shfl(sd, e);
      const int d = __shfl(sd, 16 + e);
      const uint4 a = *(const uint4*)(zb + s * HID + 8 * l16);
      const uint4 b = *(const uint4*)(zb + d * HID + 8 * l16);
      *(uint4*)&B0[sidx(r, 8 * l16)] = a;
      *(uint4*)&B1[sidx(r, 8 * l16)] = b;
      uint4 pr, ad;
      pr.x = cvtpk(blo(a.x) * blo(b.x), bhi(a.x) * bhi(b.x));
      pr.y = cvtpk(blo(a.y) * blo(b.y), bhi(a.y) * bhi(b.y));
      pr.z = cvtpk(blo(a.z) * blo(b.z), bhi(a.z) * bhi(b.z));
      pr.w = cvtpk(blo(a.w) * blo(b.w), bhi(a.w) * bhi(b.w));
      ad.x = cvtpk_abs(blo(a.x) - blo(b.x), bhi(a.x) - bhi(b.x));
      ad.y = cvtpk_abs(blo(a.y) - blo(b.y), bhi(a.y) - bhi(b.y));
      ad.z = cvtpk_abs(blo(a.z) - blo(b.z), bhi(a.z) - bhi(b.z));
      ad.w = cvtpk_abs(blo(a.w) - blo(b.w), bhi(a.w) - bhi(b.w));
      pr_pk[t] = pr;
      ad_pk[t] = ad;
    }
  } else {
#pragma unroll
    for (int t = 0; t < 8; ++t) {
      const int e = 2 * t + half;
      const int r = row0 + e;
      const int s = __shfl(sd, e);
      const int d = __shfl(sd, 16 + e);
      const float4 a = *(const float4*)(z + s * HID + 4 * li);
      const float4 b = *(const float4*)(z + d * HID + 4 * li);
      uint2 zs, zd;
      zs.x = cvtpk(a.x, a.y); zs.y = cvtpk(a.z, a.w);
      zd.x = cvtpk(b.x, b.y); zd.y = cvtpk(b.z, b.w);
      *(uint2*)&B0[sidx(r, 4 * li)] = zs;
      *(uint2*)&B1[sidx(r, 4 * li)] = zd;
      ((uint2*)pr_pk)[t].x = cvtpk(a.x * b.x, a.y * b.y);
      ((uint2*)pr_pk)[t].y = cvtpk(a.z * b.z, a.w * b.w);
      ((uint2*)ad_pk)[t].x = cvtpk_abs(a.x - b.x, a.y - b.y);
      ((uint2*)ad_pk)[t].y = cvtpk_abs(a.z - b.z, a.w - b.w);
    }
  }

  f32x16 acc[2];   // 2 m-tiles x 1 n-tile, reused for layer 1 AND 2 -> 32 AGPRs
#pragma unroll
  for (int mt = 0; mt < 2; ++mt)
#pragma unroll
    for (int rg = 0; rg < 16; ++rg) acc[mt][rg] = 0.f;

#define WFRAG(WP, KSG) (*(const short8*)((WP) + ((((KSG) * 4 + w) * 64) + lane) * 8))

  // One K=16 step: A-frag row = mt*32+(lane&31), k-col = (ks&7)*16 + hi*8.
  // ks==0 uses the pre-barrier prefetched W fragment.
#define MFMA_KS(BUF, WP, NKS, KS0, PF)                                                  \
  _Pragma("unroll")                                                                     \
  for (int ks = 0; ks < (NKS); ++ks) {                                                  \
    const int ksg = (KS0) + ks;                                                         \
    short8 bfr = (ks == 0) ? (PF) : WFRAG(WP, ksg);                                     \
    _Pragma("unroll")                                                                   \
    for (int mt = 0; mt < 2; ++mt) {                                                    \
      short8 af = *(const short8*)&BUF[sidx(mt * 32 + li, ((ksg & 7) * 16) + hi * 8)];  \
      acc[mt] = __builtin_amdgcn_mfma_f32_32x32x16_bf16(af, bfr, acc[mt], 0, 0, 0);     \
    }                                                                                   \
  }

  short8 pf = WFRAG(W1p, 0);   // prefetch across the barrier
  __syncthreads();

  // ---- P1: MFMA zs (ks 0..7)
  __builtin_amdgcn_s_setprio(1);
  MFMA_KS(B0, W1p, 8, 0, pf)
  __builtin_amdgcn_s_setprio(0);
  pf = WFRAG(W1p, 8);
  __syncthreads();

  // ---- P2: prod -> B0 (pure stores from regs); MFMA zd (ks 8..15)
  if constexpr (ZBF) {
#pragma unroll
    for (int t = 0; t < 4; ++t)
      *(uint4*)&B0[sidx(row0 + 4 * t + (lane >> 4), 8 * (lane & 15))] = pr_pk[t];
  } else {
#pragma unroll
    for (int t = 0; t < 8; ++t)
      *(uint2*)&B0[sidx(row0 + 2 * t + half, 4 * li)] = ((uint2*)pr_pk)[t];
  }
  __builtin_amdgcn_s_setprio(1);
  MFMA_KS(B1, W1p, 8, 8, pf)
  __builtin_amdgcn_s_setprio(0);
  pf = WFRAG(W1p, 16);
  __syncthreads();

  // ---- P3: absdiff -> B1 (pure stores); MFMA prod (ks 16..23)
  if constexpr (ZBF) {
#pragma unroll
    for (int t = 0; t < 4; ++t)
      *(uint4*)&B1[sidx(row0 + 4 * t + (lane >> 4), 8 * (lane & 15))] = ad_pk[t];
  } else {
#pragma unroll
    for (int t = 0; t < 8; ++t)
      *(uint2*)&B1[sidx(row0 + 2 * t + half, 4 * li)] = ((uint2*)ad_pk)[t];
  }
  __builtin_amdgcn_s_setprio(1);
  MFMA_KS(B0, W1p, 8, 16, pf)
  __builtin_amdgcn_s_setprio(0);
  pf = WFRAG(W1p, 24);
  __syncthreads();

  // ---- P4: tail -> B0 (col0 dist, cols 2..33 lr_emb; cols 34..47 stale prod
  //      * zero weight rows = 0; cols 48+ never read); MFMA absdiff (ks 24..31)
  {
    const float dv = __shfl(auxv, 32 + r15);
    if (lane < 16) B0[sidx(row0 + lane, 0)] = bf1(dv);
  }
#pragma unroll
  for (int t = 0; t < 4; ++t) {
    const int e = 4 * t + g;
    const int lrid = (int)__shfl(auxv, 48 + e);
    const float2 lv = *(const float2*)(lre + lrid * 32 + 2 * r15);
    *(uint*)&B0[sidx(row0 + e, 2 + 2 * r15)] = cvtpk(lv.x, lv.y);
  }
  __builtin_amdgcn_s_setprio(1);
  MFMA_KS(B1, W1p, 8, 24, pf)
  __builtin_amdgcn_s_setprio(0);
  pf = WFRAG(W1p, 32);
  __syncthreads();

  // ---- P5: MFMA tail (ks 32..34); h1 = relu(acc+b1) -> B1
  __builtin_amdgcn_s_setprio(1);
  MFMA_KS(B0, W1p, 3, 32, pf)
  __builtin_amdgcn_s_setprio(0);
  pf = WFRAG(W2p, 0);
  {
    const float b1v = b1[cw + li];
#pragma unroll
    for (int mt = 0; mt < 2; ++mt)
#pragma unroll
      for (int rg = 0; rg < 16; ++rg) {
        const int row = mt * 32 + (rg & 3) + 8 * (rg >> 2) + 4 * hi;
        const float h = fmaxf(acc[mt][rg] + b1v, 0.f);
        B1[sidx(row, cw + li)] = bf1(h);
      }
  }
  __syncthreads();

  // ---- P6: layer 2 (K=128, ks 0..7) from B1 (acc reused); h2 -> B0
#pragma unroll
  for (int mt = 0; mt < 2; ++mt)
#pragma unroll
    for (int rg = 0; rg < 16; ++rg) acc[mt][rg] = 0.f;
  __builtin_amdgcn_s_setprio(1);
  MFMA_KS(B1, W2p, 8, 0, pf)
  __builtin_amdgcn_s_setprio(0);
  {
    const float b2v = b2[cw + li];
#pragma unroll
    for (int mt = 0; mt < 2; ++mt)
#pragma unroll
      for (int rg = 0; rg < 16; ++rg) {
        const int row = mt * 32 + (rg & 3) + 8 * (rg >> 2) + 4 * hi;
        const float h = fmaxf(acc[mt][rg] + b2v, 0.f);
        B0[sidx(row, cw + li)] = bf1(h);
      }
  }
  __syncthreads();

  // ---- P7: layer 3 from B0: lane -> row w*16+r15, cols g*32..g*32+31
  {
    const int rr = w * 16 + r15;
    float sum = 0.f;
#pragma unroll
    for (int i = 0; i < 4; ++i) {
      const int c0 = g * 32 + i * 8;
      const uint4 hv = *(const uint4*)&B0[sidx(rr, c0)];
#pragma unroll
      for (int p = 0; p < 4; ++p) {
        const uint u = ((const uint*)&hv)[p];
        const float2 wv = *(const float2*)(W3 + c0 + 2 * p);
        sum += blo(u) * wv.x + bhi(u) * wv.y;
      }
    }
    sum += __shfl_xor(sum, 16);
    sum += __shfl_xor(sum, 32);
    if (lane < 16) out[eb + rr] = sum + b3[0];
  }
}

extern "C" void kernel_launch(void* const* d_in, const int* in_sizes, int n_in,
                              void* d_out, int out_size, void* d_ws, size_t ws_size,
                              hipStream_t stream) {
  const float* z   = (const float*)d_in[0];
  const int*   ei  = (const int*)d_in[1];
  const float* ea  = (const float*)d_in[2];
  const float* lre = (const float*)d_in[3];
  const float* W1  = (const float*)d_in[4];
  const float* b1  = (const float*)d_in[5];
  const float* W2  = (const float*)d_in[6];
  const float* b2  = (const float*)d_in[7];
  const float* W3  = (const float*)d_in[8];
  const float* b3  = (const float*)d_in[9];
  float* out = (float*)d_out;

  ushort* W1p = (ushort*)d_ws;              // 71680 bf16 = 143360 B
  ushort* W2p = W1p + (NK1 << 11);          // 16384 bf16 = 32768 B
  ushort* zb  = W2p + (8 << 11);            // 12.8M bf16 = 25.6 MB
  const size_t need = (size_t)((NK1 << 11) + (8 << 11)) * 2 + (size_t)N_NODES * HID * 2;

  prep_kernel<<<344, 256, 0, stream>>>(W1, W2, W1p, W2p);
  if (ws_size >= need) {
    prep_z<<<(N_NODES * (HID / 4) + 255) / 256, 256, 0, stream>>>(z, zb);
    edge_mlp<1><<<N_EDGES / ME, 256, 0, stream>>>(z, zb, ei, ea, lre, W1p, b1, W2p, b2, W3, b3, out);
  } else {
    edge_mlp<0><<<N_EDGES / ME, 256, 0, stream>>>(z, zb, ei, ea, lre, W1p, b1, W2p, b2, W3, b3, out);
  }
}